// Round 3
// baseline (1237.129 us; speedup 1.0000x reference)
//
#include <hip/hip_runtime.h>

#define N_USERS 100000
#define N_ITEMS 50000
#define NEDGE   800000
#define NH      128
#define NTGT    8192
#define NNODE   250000      // 50K item slots (buys) + 100K user (rev) + 100K user (fol)
#define BASE_REV 50000
#define BASE_FOL 150000
#define NBUCK   588         // 196 buys (256 nodes ea) + 196 rev (512) + 196 fol (512)
#define NSUB    (NBUCK * 8)
#define NEBLK   9375        // 3*NEDGE / 256 exactly

__device__ __forceinline__ int bucket_of(int n) {
  return (n < BASE_REV) ? (n >> 8)
       : (n < BASE_FOL) ? 196 + ((n - BASE_REV) >> 9)
                        : 392 + ((n - BASE_FOL) >> 9);
}

// ---------------------------------------------------------------- pass A: per-(bucket, blockgroup) histogram
// grid = NEBLK * 256 == 3*NEDGE exactly (no bounds check needed)
__global__ __launch_bounds__(256) void k_bcount(
    const int* __restrict__ db, const int* __restrict__ dr,
    const int* __restrict__ df, int* __restrict__ gcnt)
{
  int e = blockIdx.x * 256 + threadIdx.x;
  int g = blockIdx.x & 7;
  int n;
  if (e < NEDGE)          n = db[e];
  else if (e < 2 * NEDGE) n = BASE_REV + dr[e - NEDGE];
  else                    n = BASE_FOL + df[e - 2 * NEDGE];
  atomicAdd(&gcnt[bucket_of(n) * 8 + g], 1);
}

// ---------------------------------------------------------------- pass B: exclusive scan of 4704 counters (1 block)
__global__ __launch_bounds__(256) void k_bscan(
    const int* __restrict__ gcnt, int* __restrict__ sbase)
{
  __shared__ int carry;
  __shared__ int wsum[4];
  int t = threadIdx.x, lane = t & 63, w = t >> 6;
  if (t == 0) carry = 0;
  __syncthreads();
  for (int base = 0; base < NSUB; base += 256) {
    int orig = (base + t < NSUB) ? gcnt[base + t] : 0;
    int v = orig;
    #pragma unroll
    for (int o = 1; o < 64; o <<= 1) { int u = __shfl_up(v, o); if (lane >= o) v += u; }
    if (lane == 63) wsum[w] = v;
    __syncthreads();
    int wb = 0;
    for (int i = 0; i < w; ++i) wb += wsum[i];
    int excl = carry + wb + v - orig;
    if (base + t < NSUB) sbase[base + t] = excl;
    __syncthreads();
    if (t == 255) carry = excl + orig;
    __syncthreads();
  }
  if (threadIdx.x == 0) sbase[NSUB] = carry;   // total = 3*NEDGE
}

// ---------------------------------------------------------------- pass C: scatter edges into sub-bucket regions
// Same grid & edge->thread mapping as k_bcount so counts match fills.
// All writers of a sub-bucket share blockIdx&7 -> same XCD (heuristic) -> L2-local writes.
__global__ __launch_bounds__(256) void k_bfill(
    const int* __restrict__ sb, const int* __restrict__ db,
    const int* __restrict__ sr, const int* __restrict__ dr,
    const int* __restrict__ sf, const int* __restrict__ df,
    const int* __restrict__ sbase, int* __restrict__ gfill,
    int2* __restrict__ binned)
{
  int e = blockIdx.x * 256 + threadIdx.x;
  int g = blockIdx.x & 7;
  int n, s;
  if (e < NEDGE)          { n = db[e];                      s = sb[e]; }
  else if (e < 2 * NEDGE) { n = BASE_REV + dr[e - NEDGE];   s = sr[e - NEDGE]; }
  else                    { n = BASE_FOL + df[e - 2*NEDGE]; s = sf[e - 2*NEDGE]; }
  int sub = bucket_of(n) * 8 + g;
  int pos = atomicAdd(&gfill[sub], 1);
  binned[sbase[sub] + pos] = make_int2(s, n);
}

// ---------------------------------------------------------------- pass D: per-bucket CSR build (1 block / bucket)
// LDS histogram + scan of <=512 local nodes; esrc scatter stays within the
// bucket's contiguous ~32KB segment (single block -> single L2, one writeback).
// offs[n] = END of node n's segment (start = end - cnt[n]).
__global__ __launch_bounds__(256) void k_csr(
    const int2* __restrict__ binned, const int* __restrict__ sbase,
    int* __restrict__ cnt, int* __restrict__ offs, int* __restrict__ esrc)
{
  int b = blockIdx.x;
  int n0, S;
  if (b < 196)      { n0 = b * 256;                  S = min(256, BASE_REV - n0); }
  else if (b < 392) { n0 = BASE_REV + (b - 196) * 512; S = min(512, BASE_FOL - n0); }
  else              { n0 = BASE_FOL + (b - 392) * 512; S = min(512, NNODE - n0); }
  int e0 = sbase[b * 8];
  int e1 = sbase[(b + 1) * 8];
  int t = threadIdx.x;
  __shared__ int h[512], fl[512];
  __shared__ int wsum[4];
  h[t] = 0; h[t + 256] = 0;
  __syncthreads();
  for (int e = e0 + t; e < e1; e += 256) {
    int2 ed = binned[e];
    atomicAdd(&h[ed.y - n0], 1);
  }
  __syncthreads();
  // exclusive scan over 512 entries, 2 per thread
  int a0 = h[t * 2], a1 = h[t * 2 + 1];
  int v = a0 + a1;
  int lane = t & 63, w = t >> 6;
  #pragma unroll
  for (int o = 1; o < 64; o <<= 1) { int u = __shfl_up(v, o); if (lane >= o) v += u; }
  if (lane == 63) wsum[w] = v;
  __syncthreads();
  int wb = 0;
  for (int i = 0; i < w; ++i) wb += wsum[i];
  int excl = wb + v - (a0 + a1);           // exclusive prefix for element t*2
  fl[t * 2]     = e0 + excl;
  fl[t * 2 + 1] = e0 + excl + a0;
  int i0 = t * 2, i1 = t * 2 + 1;
  if (i0 < S) { cnt[n0 + i0] = a0; offs[n0 + i0] = e0 + excl + a0; }
  if (i1 < S) { cnt[n0 + i1] = a1; offs[n0 + i1] = e0 + excl + a0 + a1; }
  __syncthreads();
  for (int e = e0 + t; e < e1; e += 256) {
    int2 ed = binned[e];
    int p = atomicAdd(&fl[ed.y - n0], 1);
    esrc[p] = ed.x;
  }
}

// ---------------------------------------------------------------- combine Wr1+Wr2, bl1+bl2
__global__ __launch_bounds__(256) void k_combine(
    const float* __restrict__ Wr, const float* __restrict__ bl,
    float* __restrict__ Wrc, float* __restrict__ bc)
{
  int i = blockIdx.x * 256 + threadIdx.x;
  if (i < 2 * NH * NH) {
    int l = i >> 14, r = i & (NH * NH - 1);
    Wrc[i] = Wr[(l * 3 + 1) * NH * NH + r] + Wr[(l * 3 + 2) * NH * NH + r];
  } else {
    int j = i - 2 * NH * NH;
    if (j < 2 * NH) {
      int l = j >> 7, r = j & (NH - 1);
      bc[j] = bl[(l * 3 + 1) * NH + r] + bl[(l * 3 + 2) * NH + r];
    }
  }
}

// ---------------------------------------------------------------- layer-1 mean aggregation
// Half-wave (32 lanes * float4 = full 512B row) per node; 8-deep unrolled
// edge loop -> 8 outstanding row-gathers per half-wave.
__global__ __launch_bounds__(256) void k_agg1(
    const int* __restrict__ offs, const int* __restrict__ cnt,
    const int* __restrict__ esrc,
    const float* __restrict__ emb_user, const float* __restrict__ emb_item,
    float* __restrict__ meanL1)
{
  int n = blockIdx.x * 8 + (threadIdx.x >> 5);
  int sl = threadIdx.x & 31;
  if (n >= NNODE) return;
  const float4* table = (n < BASE_REV) ? (const float4*)emb_user
                      : (n < BASE_FOL) ? (const float4*)emb_item
                                       : (const float4*)emb_user;
  int end = offs[n], c = cnt[n], st = end - c;
  float ax = 0.f, ay = 0.f, az = 0.f, aw = 0.f;
  int k = st;
  for (; k + 7 < end; k += 8) {
    int s0 = esrc[k],     s1 = esrc[k + 1], s2 = esrc[k + 2], s3 = esrc[k + 3];
    int s4 = esrc[k + 4], s5 = esrc[k + 5], s6 = esrc[k + 6], s7 = esrc[k + 7];
    float4 v0 = table[(size_t)s0 * 32 + sl];
    float4 v1 = table[(size_t)s1 * 32 + sl];
    float4 v2 = table[(size_t)s2 * 32 + sl];
    float4 v3 = table[(size_t)s3 * 32 + sl];
    float4 v4 = table[(size_t)s4 * 32 + sl];
    float4 v5 = table[(size_t)s5 * 32 + sl];
    float4 v6 = table[(size_t)s6 * 32 + sl];
    float4 v7 = table[(size_t)s7 * 32 + sl];
    ax += ((v0.x + v1.x) + (v2.x + v3.x)) + ((v4.x + v5.x) + (v6.x + v7.x));
    ay += ((v0.y + v1.y) + (v2.y + v3.y)) + ((v4.y + v5.y) + (v6.y + v7.y));
    az += ((v0.z + v1.z) + (v2.z + v3.z)) + ((v4.z + v5.z) + (v6.z + v7.z));
    aw += ((v0.w + v1.w) + (v2.w + v3.w)) + ((v4.w + v5.w) + (v6.w + v7.w));
  }
  for (; k + 3 < end; k += 4) {
    int s0 = esrc[k], s1 = esrc[k + 1], s2 = esrc[k + 2], s3 = esrc[k + 3];
    float4 v0 = table[(size_t)s0 * 32 + sl];
    float4 v1 = table[(size_t)s1 * 32 + sl];
    float4 v2 = table[(size_t)s2 * 32 + sl];
    float4 v3 = table[(size_t)s3 * 32 + sl];
    ax += (v0.x + v1.x) + (v2.x + v3.x);
    ay += (v0.y + v1.y) + (v2.y + v3.y);
    az += (v0.z + v1.z) + (v2.z + v3.z);
    aw += (v0.w + v1.w) + (v2.w + v3.w);
  }
  for (; k < end; ++k) {
    float4 v = table[(size_t)esrc[k] * 32 + sl];
    ax += v.x; ay += v.y; az += v.z; aw += v.w;
  }
  float inv = 1.0f / fmaxf((float)c, 1.0f);
  float4 o; o.x = ax * inv; o.y = ay * inv; o.z = az * inv; o.w = aw * inv;
  ((float4*)meanL1)[(size_t)n * 32 + sl] = o;
}

// ---------------------------------------------------------------- layer-2 target aggregation
// Half-wave per (target, conv). which==0: rev_buys (items), also copies xsel.
__global__ __launch_bounds__(256) void k_agg_tgt(
    const int* __restrict__ tgt, const int* __restrict__ offs,
    const int* __restrict__ cnt, const int* __restrict__ esrc,
    const float* __restrict__ xu1, const float* __restrict__ xi1,
    float* __restrict__ mrev, float* __restrict__ mfol, float* __restrict__ xsel)
{
  int hw = blockIdx.x * 8 + (threadIdx.x >> 5);
  int sl = threadIdx.x & 31;
  int t = hw >> 1, which = hw & 1;
  if (t >= NTGT) return;
  int u = tgt[t];
  int n = (which ? BASE_FOL : BASE_REV) + u;
  const float4* table = which ? (const float4*)xu1 : (const float4*)xi1;
  int end = offs[n], c = cnt[n], st = end - c;
  float ax = 0.f, ay = 0.f, az = 0.f, aw = 0.f;
  int k = st;
  for (; k + 7 < end; k += 8) {
    int s0 = esrc[k],     s1 = esrc[k + 1], s2 = esrc[k + 2], s3 = esrc[k + 3];
    int s4 = esrc[k + 4], s5 = esrc[k + 5], s6 = esrc[k + 6], s7 = esrc[k + 7];
    float4 v0 = table[(size_t)s0 * 32 + sl];
    float4 v1 = table[(size_t)s1 * 32 + sl];
    float4 v2 = table[(size_t)s2 * 32 + sl];
    float4 v3 = table[(size_t)s3 * 32 + sl];
    float4 v4 = table[(size_t)s4 * 32 + sl];
    float4 v5 = table[(size_t)s5 * 32 + sl];
    float4 v6 = table[(size_t)s6 * 32 + sl];
    float4 v7 = table[(size_t)s7 * 32 + sl];
    ax += ((v0.x + v1.x) + (v2.x + v3.x)) + ((v4.x + v5.x) + (v6.x + v7.x));
    ay += ((v0.y + v1.y) + (v2.y + v3.y)) + ((v4.y + v5.y) + (v6.y + v7.y));
    az += ((v0.z + v1.z) + (v2.z + v3.z)) + ((v4.z + v5.z) + (v6.z + v7.z));
    aw += ((v0.w + v1.w) + (v2.w + v3.w)) + ((v4.w + v5.w) + (v6.w + v7.w));
  }
  for (; k + 3 < end; k += 4) {
    int s0 = esrc[k], s1 = esrc[k + 1], s2 = esrc[k + 2], s3 = esrc[k + 3];
    float4 v0 = table[(size_t)s0 * 32 + sl];
    float4 v1 = table[(size_t)s1 * 32 + sl];
    float4 v2 = table[(size_t)s2 * 32 + sl];
    float4 v3 = table[(size_t)s3 * 32 + sl];
    ax += (v0.x + v1.x) + (v2.x + v3.x);
    ay += (v0.y + v1.y) + (v2.y + v3.y);
    az += (v0.z + v1.z) + (v2.z + v3.z);
    aw += (v0.w + v1.w) + (v2.w + v3.w);
  }
  for (; k < end; ++k) {
    float4 v = table[(size_t)esrc[k] * 32 + sl];
    ax += v.x; ay += v.y; az += v.z; aw += v.w;
  }
  float inv = 1.0f / fmaxf((float)c, 1.0f);
  float4 o; o.x = ax * inv; o.y = ay * inv; o.z = az * inv; o.w = aw * inv;
  if (which) {
    ((float4*)mfol)[(size_t)t * 32 + sl] = o;
  } else {
    ((float4*)mrev)[(size_t)t * 32 + sl] = o;
    ((float4*)xsel)[(size_t)t * 32 + sl] = ((const float4*)xu1)[(size_t)u * 32 + sl];
  }
}

// ---------------------------------------------------------------- fused multi-term GEMM + bias + LN + ReLU
// out[r][c] = relu(LN_row( sum_terms A_t[r][:] . W_t[c][:] + bias[c] ))
// Block: 256 threads, tile 64 rows x 128 cols; 8x4 acc per thread.
__global__ __launch_bounds__(256) void k_gemm_ln(
    const float* __restrict__ A0, const float* __restrict__ W0,
    const float* __restrict__ A1, const float* __restrict__ W1,
    const float* __restrict__ A2, const float* __restrict__ W2,
    const float* __restrict__ bias, const float* __restrict__ lng,
    const float* __restrict__ lnb, float* __restrict__ out, int M)
{
  const int t = threadIdx.x;
  const int tx = t & 31, ty = t >> 5;          // tx: col-group (4 cols), ty: row-group (8 rows)
  const int rowbase = blockIdx.x * 64;
  __shared__ float As[32][68];                  // [kk][row]
  __shared__ float Ws[32 * 132];                // [kk][col], padded

  float acc[8][4];
  #pragma unroll
  for (int i = 0; i < 8; ++i)
    #pragma unroll
    for (int j = 0; j < 4; ++j) acc[i][j] = 0.f;

  const int arow = t >> 2;                // 0..63
  const int ak8  = (t & 3) * 8;           // 0,8,16,24

  #pragma unroll
  for (int term = 0; term < 3; ++term) {
    const float* A = (term == 0) ? A0 : (term == 1) ? A1 : A2;
    const float* W = (term == 0) ? W0 : (term == 1) ? W1 : W2;
    if (A == nullptr) continue;
    for (int kc = 0; kc < NH; kc += 32) {
      {
        int gr = rowbase + arow; if (gr > M - 1) gr = M - 1;
        const float* ap = &A[(size_t)gr * NH + kc + ak8];
        float4 v0 = *(const float4*)(ap);
        float4 v1 = *(const float4*)(ap + 4);
        As[ak8 + 0][arow] = v0.x; As[ak8 + 1][arow] = v0.y;
        As[ak8 + 2][arow] = v0.z; As[ak8 + 3][arow] = v0.w;
        As[ak8 + 4][arow] = v1.x; As[ak8 + 5][arow] = v1.y;
        As[ak8 + 6][arow] = v1.z; As[ak8 + 7][arow] = v1.w;
      }
      #pragma unroll
      for (int i = 0; i < 4; ++i) {
        int linear = t * 4 + i * 1024;
        int j = linear >> 5, k4 = linear & 31;
        float4 v = *(const float4*)&W[j * NH + kc + k4];
        Ws[(k4 + 0) * 132 + j] = v.x; Ws[(k4 + 1) * 132 + j] = v.y;
        Ws[(k4 + 2) * 132 + j] = v.z; Ws[(k4 + 3) * 132 + j] = v.w;
      }
      __syncthreads();
      #pragma unroll
      for (int kk = 0; kk < 32; ++kk) {
        float4 alo = *(const float4*)&As[kk][ty * 8];
        float4 ahi = *(const float4*)&As[kk][ty * 8 + 4];
        float4 w4  = *(const float4*)&Ws[kk * 132 + tx * 4];
        float ar[8] = {alo.x, alo.y, alo.z, alo.w, ahi.x, ahi.y, ahi.z, ahi.w};
        float wr[4] = {w4.x, w4.y, w4.z, w4.w};
        #pragma unroll
        for (int i = 0; i < 8; ++i)
          #pragma unroll
          for (int j = 0; j < 4; ++j)
            acc[i][j] = fmaf(ar[i], wr[j], acc[i][j]);
      }
      __syncthreads();
    }
  }

  float4 b4 = *(const float4*)&bias[tx * 4];
  float4 g4 = *(const float4*)&lng[tx * 4];
  float4 l4 = *(const float4*)&lnb[tx * 4];
  float bb[4] = {b4.x, b4.y, b4.z, b4.w};
  float gg[4] = {g4.x, g4.y, g4.z, g4.w};
  float ll[4] = {l4.x, l4.y, l4.z, l4.w};

  #pragma unroll
  for (int i = 0; i < 8; ++i) {
    float s = 0.f, ss = 0.f;
    #pragma unroll
    for (int j = 0; j < 4; ++j) {
      float v = acc[i][j] + bb[j];
      acc[i][j] = v;
      s += v; ss += v * v;
    }
    #pragma unroll
    for (int o = 1; o < 32; o <<= 1) { s += __shfl_xor(s, o); ss += __shfl_xor(ss, o); }
    float mu = s * (1.0f / 128.0f);
    float var = ss * (1.0f / 128.0f) - mu * mu;
    float rinv = rsqrtf(var + 1e-5f);
    int gr = rowbase + ty * 8 + i;
    if (gr < M) {
      float4 y;
      y.x = fmaxf((acc[i][0] - mu) * rinv * gg[0] + ll[0], 0.f);
      y.y = fmaxf((acc[i][1] - mu) * rinv * gg[1] + ll[1], 0.f);
      y.z = fmaxf((acc[i][2] - mu) * rinv * gg[2] + ll[2], 0.f);
      y.w = fmaxf((acc[i][3] - mu) * rinv * gg[3] + ll[3], 0.f);
      *(float4*)&out[(size_t)gr * NH + tx * 4] = y;
    }
  }
}

// ---------------------------------------------------------------- final MLP: relu(h@W1.T+b1)@W2.T+b2
__global__ __launch_bounds__(256) void k_mlp(
    const float* __restrict__ h2, const float* __restrict__ W1,
    const float* __restrict__ b1, const float* __restrict__ W2,
    const float* __restrict__ b2, float* __restrict__ out)
{
  __shared__ float W1s[64 * 129];
  __shared__ float b1s[64];
  __shared__ float W2s[64];
  __shared__ float sx[4][128];
  int t = threadIdx.x;
  #pragma unroll
  for (int i = 0; i < 32; ++i) {
    int idx = t + 256 * i;             // 0..8191
    int j = idx >> 7, k = idx & 127;
    W1s[j * 129 + k] = W1[idx];
  }
  if (t < 64) { b1s[t] = b1[t]; W2s[t] = W2[t]; }
  __syncthreads();
  int w = t >> 6, lane = t & 63;
  float b2v = b2[0];
  for (int it = 0; it < 8; ++it) {
    int r = blockIdx.x * 32 + it * 4 + w;
    sx[w][lane]      = h2[(size_t)r * NH + lane];
    sx[w][lane + 64] = h2[(size_t)r * NH + lane + 64];
    __syncthreads();
    float h = b1s[lane];
    #pragma unroll
    for (int k = 0; k < 128; ++k) h = fmaf(sx[w][k], W1s[lane * 129 + k], h);
    h = fmaxf(h, 0.f);
    float p = h * W2s[lane];
    #pragma unroll
    for (int o = 32; o > 0; o >>= 1) p += __shfl_down(p, o);
    if (lane == 0) out[r] = p + b2v;
    __syncthreads();
  }
}

// ---------------------------------------------------------------- launch
extern "C" void kernel_launch(void* const* d_in, const int* in_sizes, int n_in,
                              void* d_out, int out_size, void* d_ws, size_t ws_size,
                              hipStream_t stream)
{
  const float* emb_user = (const float*)d_in[0];
  const float* emb_item = (const float*)d_in[1];
  const float* Wl   = (const float*)d_in[2];   // [2,3,128,128]
  const float* bl   = (const float*)d_in[3];   // [2,3,128]
  const float* Wr   = (const float*)d_in[4];   // [2,3,128,128]
  const float* ln_g = (const float*)d_in[5];   // [2,2,128]
  const float* ln_b = (const float*)d_in[6];   // [2,2,128]
  const float* W1   = (const float*)d_in[7];   // [64,128]
  const float* b1   = (const float*)d_in[8];   // [64]
  const float* W2   = (const float*)d_in[9];   // [1,64]
  const float* b2   = (const float*)d_in[10];  // [1]
  const int* src_buys = (const int*)d_in[11];
  const int* dst_buys = (const int*)d_in[12];
  const int* src_rev  = (const int*)d_in[13];
  const int* dst_rev  = (const int*)d_in[14];
  const int* src_fol  = (const int*)d_in[15];
  const int* dst_fol  = (const int*)d_in[16];
  const int* tgt      = (const int*)d_in[17];
  float* outp = (float*)d_out;

  char* wp = (char*)d_ws;
  size_t ob = 0;
  auto take = [&](size_t bytes) -> void* {
    void* p = wp + ob;
    ob += (bytes + 255) & ~(size_t)255;
    return p;
  };
  int*   cnt    = (int*)  take((size_t)NNODE * 4);
  int*   offs   = (int*)  take((size_t)NNODE * 4);
  int*   gcnt   = (int*)  take((size_t)2 * NSUB * 4);   // gcnt + gfill, one memset
  int*   gfill  = gcnt + NSUB;
  int*   sbase  = (int*)  take((size_t)(NSUB + 1) * 4);
  int*   esrc   = (int*)  take((size_t)3 * NEDGE * 4);
  float* Wrc    = (float*)take((size_t)2 * NH * NH * 4);
  float* bc     = (float*)take((size_t)2 * NH * 4);
  float* meanL1 = (float*)take((size_t)NNODE * NH * 4);
  float* xu1    = (float*)take((size_t)N_USERS * NH * 4);
  float* xi1    = (float*)take((size_t)N_ITEMS * NH * 4);
  float* mrev2  = (float*)take((size_t)NTGT * NH * 4);
  float* mfol2  = (float*)take((size_t)NTGT * NH * 4);
  float* xsel2  = (float*)take((size_t)NTGT * NH * 4);
  float* h2     = (float*)take((size_t)NTGT * NH * 4);
  // binned edge buffer (19.2 MB) aliases meanL1 (128 MB): binned is consumed
  // by k_csr before k_agg1 writes meanL1.
  int2*  binned = (int2*)meanL1;

  hipMemsetAsync(gcnt, 0, (size_t)2 * NSUB * 4, stream);

  k_combine<<<(2 * NH * NH + 2 * NH + 255) / 256, 256, 0, stream>>>(Wr, bl, Wrc, bc);
  k_bcount<<<NEBLK, 256, 0, stream>>>(dst_buys, dst_rev, dst_fol, gcnt);
  k_bscan<<<1, 256, 0, stream>>>(gcnt, sbase);
  k_bfill<<<NEBLK, 256, 0, stream>>>(
      src_buys, dst_buys, src_rev, dst_rev, src_fol, dst_fol, sbase, gfill, binned);
  k_csr<<<NBUCK, 256, 0, stream>>>(binned, sbase, cnt, offs, esrc);
  k_agg1<<<(NNODE + 7) / 8, 256, 0, stream>>>(offs, cnt, esrc, emb_user, emb_item, meanL1);

  // layer-1 item: relu(LN(mean_buys@Wl00.T + xi0@Wr00.T + bl00))
  k_gemm_ln<<<(N_ITEMS + 63) / 64, 256, 0, stream>>>(
      meanL1, Wl + 0 * NH * NH,
      emb_item, Wr + 0 * NH * NH,
      nullptr, nullptr,
      bl + 0 * NH, ln_g + 1 * NH, ln_b + 1 * NH, xi1, N_ITEMS);

  // layer-1 user: relu(LN(mean_rev@Wl01.T + mean_fol@Wl02.T + xu0@(Wr01+Wr02).T + bl01+bl02))
  k_gemm_ln<<<(N_USERS + 63) / 64, 256, 0, stream>>>(
      meanL1 + (size_t)BASE_REV * NH, Wl + 1 * NH * NH,
      meanL1 + (size_t)BASE_FOL * NH, Wl + 2 * NH * NH,
      emb_user, Wrc,
      bc, ln_g + 0 * NH, ln_b + 0 * NH, xu1, N_USERS);

  // layer-2 aggregation at targets only (item update is dead code)
  k_agg_tgt<<<(2 * NTGT + 7) / 8, 256, 0, stream>>>(tgt, offs, cnt, esrc, xu1, xi1, mrev2, mfol2, xsel2);

  // layer-2 user at targets
  k_gemm_ln<<<(NTGT + 63) / 64, 256, 0, stream>>>(
      mrev2, Wl + (1 * 3 + 1) * NH * NH,
      mfol2, Wl + (1 * 3 + 2) * NH * NH,
      xsel2, Wrc + NH * NH,
      bc + NH, ln_g + 2 * NH, ln_b + 2 * NH, h2, NTGT);

  // final MLP
  k_mlp<<<NTGT / 32, 256, 0, stream>>>(h2, W1, b1, W2, b2, outp);
}

// Round 4
// 635.454 us; speedup vs baseline: 1.9468x; 1.9468x over previous
//
#include <hip/hip_runtime.h>

#define N_USERS 100000
#define N_ITEMS 50000
#define NEDGE   800000
#define NH      128
#define NTGT    8192
#define NNODE   250000      // 50K item slots (buys) + 100K user (rev) + 100K user (fol)
#define BASE_REV 50000
#define BASE_FOL 150000
#define NBUCK   588         // 196 buys (256 nodes) + 196 rev (512) + 196 fol (512)
#define NBLK    384         // binning blocks
#define NPB     6250        // edges per binning block: 384*6250 = 2400000 exactly
#define NRUN    (NBUCK * NBLK)        // 225792 per-(bucket,block) runs
#define NSCANB  441                   // 225792 / 512 exactly

__device__ __forceinline__ int bucket_of(int n) {
  return (n < BASE_REV) ? (n >> 8)
       : (n < BASE_FOL) ? 196 + ((n - BASE_REV) >> 9)
                        : 392 + ((n - BASE_FOL) >> 9);
}

// ---------------------------------------------------------------- pass A: per-(bucket,block) histogram, LDS only
__global__ __launch_bounds__(256) void k_pcount(
    const int* __restrict__ db, const int* __restrict__ dr,
    const int* __restrict__ df, int* __restrict__ cntBB)
{
  __shared__ int h[NBUCK];
  int t = threadIdx.x, blk = blockIdx.x;
  for (int j = t; j < NBUCK; j += 256) h[j] = 0;
  __syncthreads();
  int ebase = blk * NPB;
  for (int i = t; i < NPB; i += 256) {
    int e = ebase + i, n;
    if (e < NEDGE)          n = db[e];
    else if (e < 2 * NEDGE) n = BASE_REV + dr[e - NEDGE];
    else                    n = BASE_FOL + df[e - 2 * NEDGE];
    atomicAdd(&h[bucket_of(n)], 1);
  }
  __syncthreads();
  for (int j = t; j < NBUCK; j += 256) cntBB[j * NBLK + blk] = h[j];
}

// ---------------------------------------------------------------- scan of 225792 counts (3 tiny kernels)
__global__ __launch_bounds__(256) void k_scanA(const int* __restrict__ cntBB,
                                               int* __restrict__ partial)
{
  int t = threadIdx.x;
  int base = blockIdx.x * 512;
  int s = cntBB[base + t] + cntBB[base + 256 + t];
  __shared__ int red[256];
  red[t] = s; __syncthreads();
  for (int d = 128; d > 0; d >>= 1) { if (t < d) red[t] += red[t + d]; __syncthreads(); }
  if (t == 0) partial[blockIdx.x] = red[0];
}

__global__ __launch_bounds__(256) void k_scanB(const int* __restrict__ partial,
                                               int* __restrict__ pbase)
{
  __shared__ int carry;
  __shared__ int wsum[4];
  int t = threadIdx.x, lane = t & 63, w = t >> 6;
  if (t == 0) carry = 0;
  __syncthreads();
  for (int base = 0; base < NSCANB; base += 256) {
    int orig = (base + t < NSCANB) ? partial[base + t] : 0;
    int v = orig;
    #pragma unroll
    for (int o = 1; o < 64; o <<= 1) { int u = __shfl_up(v, o); if (lane >= o) v += u; }
    if (lane == 63) wsum[w] = v;
    __syncthreads();
    int wb = 0;
    for (int i = 0; i < w; ++i) wb += wsum[i];
    int excl = carry + wb + v - orig;
    if (base + t < NSCANB) pbase[base + t] = excl;
    __syncthreads();
    if (t == 255) carry = excl + orig;
    __syncthreads();
  }
}

__global__ __launch_bounds__(256) void k_scanC(const int* __restrict__ cntBB,
                                               const int* __restrict__ pbase,
                                               int* __restrict__ sscan)
{
  int t = threadIdx.x, blk = blockIdx.x;
  int base = blk * 512;
  int a0 = cntBB[base + t * 2], a1 = cntBB[base + t * 2 + 1];
  int sum = a0 + a1;
  int lane = t & 63, w = t >> 6;
  int v = sum;
  #pragma unroll
  for (int o = 1; o < 64; o <<= 1) { int u = __shfl_up(v, o); if (lane >= o) v += u; }
  __shared__ int wsum[4];
  if (lane == 63) wsum[w] = v;
  __syncthreads();
  int wb = 0;
  for (int i = 0; i < w; ++i) wb += wsum[i];
  int excl = wb + v - sum;
  int P = pbase[blk];
  sscan[base + t * 2]     = P + excl;
  sscan[base + t * 2 + 1] = P + excl + a0;
  if (blk == NSCANB - 1 && t == 255)
    sscan[NRUN] = P + wsum[0] + wsum[1] + wsum[2] + wsum[3];   // == 3*NEDGE
}

// ---------------------------------------------------------------- pass B: scatter into pre-reserved runs (LDS cursors only)
// binned entry packs (local_node_in_bucket << 17) | src  (src < 2^17, local < 512)
__global__ __launch_bounds__(256) void k_pfill(
    const int* __restrict__ sb, const int* __restrict__ db,
    const int* __restrict__ sr, const int* __restrict__ dr,
    const int* __restrict__ sf, const int* __restrict__ df,
    const int* __restrict__ sscan, int* __restrict__ binned)
{
  __shared__ int cur[NBUCK];
  int t = threadIdx.x, blk = blockIdx.x;
  for (int j = t; j < NBUCK; j += 256) cur[j] = sscan[j * NBLK + blk];
  __syncthreads();
  int ebase = blk * NPB;
  for (int i = t; i < NPB; i += 256) {
    int e = ebase + i, n, s;
    if (e < NEDGE)          { n = db[e];                      s = sb[e]; }
    else if (e < 2 * NEDGE) { n = BASE_REV + dr[e - NEDGE];   s = sr[e - NEDGE]; }
    else                    { n = BASE_FOL + df[e - 2*NEDGE]; s = sf[e - 2*NEDGE]; }
    int b = bucket_of(n);
    int local = (n < BASE_REV) ? (n & 255)
              : (n < BASE_FOL) ? ((n - BASE_REV) & 511)
                               : ((n - BASE_FOL) & 511);
    int pos = atomicAdd(&cur[b], 1);
    binned[pos] = (local << 17) | s;
  }
}

// ---------------------------------------------------------------- pass C: per-bucket CSR build (1 block / bucket)
// Bucket b's edges are dense in binned[sscan[b*NBLK] .. sscan[(b+1)*NBLK]).
// offs[n] = END of node n's esrc segment (start = end - cnt[n]).
__global__ __launch_bounds__(256) void k_csr(
    const int* __restrict__ binned, const int* __restrict__ sscan,
    int* __restrict__ cnt, int* __restrict__ offs, int* __restrict__ esrc)
{
  int b = blockIdx.x;
  int n0, S;
  if (b < 196)      { n0 = b * 256;                    S = min(256, BASE_REV - n0); }
  else if (b < 392) { n0 = BASE_REV + (b - 196) * 512; S = min(512, BASE_FOL - n0); }
  else              { n0 = BASE_FOL + (b - 392) * 512; S = min(512, NNODE - n0); }
  int e0 = sscan[b * NBLK];
  int e1 = sscan[(b + 1) * NBLK];
  int t = threadIdx.x;
  __shared__ int h[512], fl[512];
  __shared__ int wsum[4];
  h[t] = 0; h[t + 256] = 0;
  __syncthreads();
  for (int e = e0 + t; e < e1; e += 256)
    atomicAdd(&h[binned[e] >> 17], 1);
  __syncthreads();
  // exclusive scan over 512 entries, 2 per thread
  int a0 = h[t * 2], a1 = h[t * 2 + 1];
  int v = a0 + a1;
  int lane = t & 63, w = t >> 6;
  #pragma unroll
  for (int o = 1; o < 64; o <<= 1) { int u = __shfl_up(v, o); if (lane >= o) v += u; }
  if (lane == 63) wsum[w] = v;
  __syncthreads();
  int wb = 0;
  for (int i = 0; i < w; ++i) wb += wsum[i];
  int excl = wb + v - (a0 + a1);
  fl[t * 2]     = e0 + excl;
  fl[t * 2 + 1] = e0 + excl + a0;
  if (t * 2 < S)     { cnt[n0 + t * 2]     = a0; offs[n0 + t * 2]     = e0 + excl + a0; }
  if (t * 2 + 1 < S) { cnt[n0 + t * 2 + 1] = a1; offs[n0 + t * 2 + 1] = e0 + excl + a0 + a1; }
  __syncthreads();
  for (int e = e0 + t; e < e1; e += 256) {
    int v2 = binned[e];
    int p = atomicAdd(&fl[v2 >> 17], 1);
    esrc[p] = v2 & 0x1FFFF;
  }
}

// ---------------------------------------------------------------- combine Wr1+Wr2, bl1+bl2
__global__ __launch_bounds__(256) void k_combine(
    const float* __restrict__ Wr, const float* __restrict__ bl,
    float* __restrict__ Wrc, float* __restrict__ bc)
{
  int i = blockIdx.x * 256 + threadIdx.x;
  if (i < 2 * NH * NH) {
    int l = i >> 14, r = i & (NH * NH - 1);
    Wrc[i] = Wr[(l * 3 + 1) * NH * NH + r] + Wr[(l * 3 + 2) * NH * NH + r];
  } else {
    int j = i - 2 * NH * NH;
    if (j < 2 * NH) {
      int l = j >> 7, r = j & (NH - 1);
      bc[j] = bl[(l * 3 + 1) * NH + r] + bl[(l * 3 + 2) * NH + r];
    }
  }
}

// ---------------------------------------------------------------- layer-1 mean aggregation
// Half-wave (32 lanes * float4 = full 512B row) per node; 8-deep unrolled
// edge loop -> 8 outstanding row-gathers per half-wave.
__global__ __launch_bounds__(256) void k_agg1(
    const int* __restrict__ offs, const int* __restrict__ cnt,
    const int* __restrict__ esrc,
    const float* __restrict__ emb_user, const float* __restrict__ emb_item,
    float* __restrict__ meanL1)
{
  int n = blockIdx.x * 8 + (threadIdx.x >> 5);
  int sl = threadIdx.x & 31;
  if (n >= NNODE) return;
  const float4* table = (n < BASE_REV) ? (const float4*)emb_user
                      : (n < BASE_FOL) ? (const float4*)emb_item
                                       : (const float4*)emb_user;
  int end = offs[n], c = cnt[n], st = end - c;
  float ax = 0.f, ay = 0.f, az = 0.f, aw = 0.f;
  int k = st;
  for (; k + 7 < end; k += 8) {
    int s0 = esrc[k],     s1 = esrc[k + 1], s2 = esrc[k + 2], s3 = esrc[k + 3];
    int s4 = esrc[k + 4], s5 = esrc[k + 5], s6 = esrc[k + 6], s7 = esrc[k + 7];
    float4 v0 = table[(size_t)s0 * 32 + sl];
    float4 v1 = table[(size_t)s1 * 32 + sl];
    float4 v2 = table[(size_t)s2 * 32 + sl];
    float4 v3 = table[(size_t)s3 * 32 + sl];
    float4 v4 = table[(size_t)s4 * 32 + sl];
    float4 v5 = table[(size_t)s5 * 32 + sl];
    float4 v6 = table[(size_t)s6 * 32 + sl];
    float4 v7 = table[(size_t)s7 * 32 + sl];
    ax += ((v0.x + v1.x) + (v2.x + v3.x)) + ((v4.x + v5.x) + (v6.x + v7.x));
    ay += ((v0.y + v1.y) + (v2.y + v3.y)) + ((v4.y + v5.y) + (v6.y + v7.y));
    az += ((v0.z + v1.z) + (v2.z + v3.z)) + ((v4.z + v5.z) + (v6.z + v7.z));
    aw += ((v0.w + v1.w) + (v2.w + v3.w)) + ((v4.w + v5.w) + (v6.w + v7.w));
  }
  for (; k + 3 < end; k += 4) {
    int s0 = esrc[k], s1 = esrc[k + 1], s2 = esrc[k + 2], s3 = esrc[k + 3];
    float4 v0 = table[(size_t)s0 * 32 + sl];
    float4 v1 = table[(size_t)s1 * 32 + sl];
    float4 v2 = table[(size_t)s2 * 32 + sl];
    float4 v3 = table[(size_t)s3 * 32 + sl];
    ax += (v0.x + v1.x) + (v2.x + v3.x);
    ay += (v0.y + v1.y) + (v2.y + v3.y);
    az += (v0.z + v1.z) + (v2.z + v3.z);
    aw += (v0.w + v1.w) + (v2.w + v3.w);
  }
  for (; k < end; ++k) {
    float4 v = table[(size_t)esrc[k] * 32 + sl];
    ax += v.x; ay += v.y; az += v.z; aw += v.w;
  }
  float inv = 1.0f / fmaxf((float)c, 1.0f);
  float4 o; o.x = ax * inv; o.y = ay * inv; o.z = az * inv; o.w = aw * inv;
  ((float4*)meanL1)[(size_t)n * 32 + sl] = o;
}

// ---------------------------------------------------------------- layer-2 target aggregation
__global__ __launch_bounds__(256) void k_agg_tgt(
    const int* __restrict__ tgt, const int* __restrict__ offs,
    const int* __restrict__ cnt, const int* __restrict__ esrc,
    const float* __restrict__ xu1, const float* __restrict__ xi1,
    float* __restrict__ mrev, float* __restrict__ mfol, float* __restrict__ xsel)
{
  int hw = blockIdx.x * 8 + (threadIdx.x >> 5);
  int sl = threadIdx.x & 31;
  int t = hw >> 1, which = hw & 1;
  if (t >= NTGT) return;
  int u = tgt[t];
  int n = (which ? BASE_FOL : BASE_REV) + u;
  const float4* table = which ? (const float4*)xu1 : (const float4*)xi1;
  int end = offs[n], c = cnt[n], st = end - c;
  float ax = 0.f, ay = 0.f, az = 0.f, aw = 0.f;
  int k = st;
  for (; k + 7 < end; k += 8) {
    int s0 = esrc[k],     s1 = esrc[k + 1], s2 = esrc[k + 2], s3 = esrc[k + 3];
    int s4 = esrc[k + 4], s5 = esrc[k + 5], s6 = esrc[k + 6], s7 = esrc[k + 7];
    float4 v0 = table[(size_t)s0 * 32 + sl];
    float4 v1 = table[(size_t)s1 * 32 + sl];
    float4 v2 = table[(size_t)s2 * 32 + sl];
    float4 v3 = table[(size_t)s3 * 32 + sl];
    float4 v4 = table[(size_t)s4 * 32 + sl];
    float4 v5 = table[(size_t)s5 * 32 + sl];
    float4 v6 = table[(size_t)s6 * 32 + sl];
    float4 v7 = table[(size_t)s7 * 32 + sl];
    ax += ((v0.x + v1.x) + (v2.x + v3.x)) + ((v4.x + v5.x) + (v6.x + v7.x));
    ay += ((v0.y + v1.y) + (v2.y + v3.y)) + ((v4.y + v5.y) + (v6.y + v7.y));
    az += ((v0.z + v1.z) + (v2.z + v3.z)) + ((v4.z + v5.z) + (v6.z + v7.z));
    aw += ((v0.w + v1.w) + (v2.w + v3.w)) + ((v4.w + v5.w) + (v6.w + v7.w));
  }
  for (; k + 3 < end; k += 4) {
    int s0 = esrc[k], s1 = esrc[k + 1], s2 = esrc[k + 2], s3 = esrc[k + 3];
    float4 v0 = table[(size_t)s0 * 32 + sl];
    float4 v1 = table[(size_t)s1 * 32 + sl];
    float4 v2 = table[(size_t)s2 * 32 + sl];
    float4 v3 = table[(size_t)s3 * 32 + sl];
    ax += (v0.x + v1.x) + (v2.x + v3.x);
    ay += (v0.y + v1.y) + (v2.y + v3.y);
    az += (v0.z + v1.z) + (v2.z + v3.z);
    aw += (v0.w + v1.w) + (v2.w + v3.w);
  }
  for (; k < end; ++k) {
    float4 v = table[(size_t)esrc[k] * 32 + sl];
    ax += v.x; ay += v.y; az += v.z; aw += v.w;
  }
  float inv = 1.0f / fmaxf((float)c, 1.0f);
  float4 o; o.x = ax * inv; o.y = ay * inv; o.z = az * inv; o.w = aw * inv;
  if (which) {
    ((float4*)mfol)[(size_t)t * 32 + sl] = o;
  } else {
    ((float4*)mrev)[(size_t)t * 32 + sl] = o;
    ((float4*)xsel)[(size_t)t * 32 + sl] = ((const float4*)xu1)[(size_t)u * 32 + sl];
  }
}

// ---------------------------------------------------------------- fused multi-term GEMM + bias + LN + ReLU
__global__ __launch_bounds__(256) void k_gemm_ln(
    const float* __restrict__ A0, const float* __restrict__ W0,
    const float* __restrict__ A1, const float* __restrict__ W1,
    const float* __restrict__ A2, const float* __restrict__ W2,
    const float* __restrict__ bias, const float* __restrict__ lng,
    const float* __restrict__ lnb, float* __restrict__ out, int M)
{
  const int t = threadIdx.x;
  const int tx = t & 31, ty = t >> 5;
  const int rowbase = blockIdx.x * 64;
  __shared__ float As[32][68];
  __shared__ float Ws[32 * 132];

  float acc[8][4];
  #pragma unroll
  for (int i = 0; i < 8; ++i)
    #pragma unroll
    for (int j = 0; j < 4; ++j) acc[i][j] = 0.f;

  const int arow = t >> 2;
  const int ak8  = (t & 3) * 8;

  #pragma unroll
  for (int term = 0; term < 3; ++term) {
    const float* A = (term == 0) ? A0 : (term == 1) ? A1 : A2;
    const float* W = (term == 0) ? W0 : (term == 1) ? W1 : W2;
    if (A == nullptr) continue;
    for (int kc = 0; kc < NH; kc += 32) {
      {
        int gr = rowbase + arow; if (gr > M - 1) gr = M - 1;
        const float* ap = &A[(size_t)gr * NH + kc + ak8];
        float4 v0 = *(const float4*)(ap);
        float4 v1 = *(const float4*)(ap + 4);
        As[ak8 + 0][arow] = v0.x; As[ak8 + 1][arow] = v0.y;
        As[ak8 + 2][arow] = v0.z; As[ak8 + 3][arow] = v0.w;
        As[ak8 + 4][arow] = v1.x; As[ak8 + 5][arow] = v1.y;
        As[ak8 + 6][arow] = v1.z; As[ak8 + 7][arow] = v1.w;
      }
      #pragma unroll
      for (int i = 0; i < 4; ++i) {
        int linear = t * 4 + i * 1024;
        int j = linear >> 5, k4 = linear & 31;
        float4 v = *(const float4*)&W[j * NH + kc + k4];
        Ws[(k4 + 0) * 132 + j] = v.x; Ws[(k4 + 1) * 132 + j] = v.y;
        Ws[(k4 + 2) * 132 + j] = v.z; Ws[(k4 + 3) * 132 + j] = v.w;
      }
      __syncthreads();
      #pragma unroll
      for (int kk = 0; kk < 32; ++kk) {
        float4 alo = *(const float4*)&As[kk][ty * 8];
        float4 ahi = *(const float4*)&As[kk][ty * 8 + 4];
        float4 w4  = *(const float4*)&Ws[kk * 132 + tx * 4];
        float ar[8] = {alo.x, alo.y, alo.z, alo.w, ahi.x, ahi.y, ahi.z, ahi.w};
        float wr[4] = {w4.x, w4.y, w4.z, w4.w};
        #pragma unroll
        for (int i = 0; i < 8; ++i)
          #pragma unroll
          for (int j = 0; j < 4; ++j)
            acc[i][j] = fmaf(ar[i], wr[j], acc[i][j]);
      }
      __syncthreads();
    }
  }

  float4 b4 = *(const float4*)&bias[tx * 4];
  float4 g4 = *(const float4*)&lng[tx * 4];
  float4 l4 = *(const float4*)&lnb[tx * 4];
  float bb[4] = {b4.x, b4.y, b4.z, b4.w};
  float gg[4] = {g4.x, g4.y, g4.z, g4.w};
  float ll[4] = {l4.x, l4.y, l4.z, l4.w};

  #pragma unroll
  for (int i = 0; i < 8; ++i) {
    float s = 0.f, ss = 0.f;
    #pragma unroll
    for (int j = 0; j < 4; ++j) {
      float v = acc[i][j] + bb[j];
      acc[i][j] = v;
      s += v; ss += v * v;
    }
    #pragma unroll
    for (int o = 1; o < 32; o <<= 1) { s += __shfl_xor(s, o); ss += __shfl_xor(ss, o); }
    float mu = s * (1.0f / 128.0f);
    float var = ss * (1.0f / 128.0f) - mu * mu;
    float rinv = rsqrtf(var + 1e-5f);
    int gr = rowbase + ty * 8 + i;
    if (gr < M) {
      float4 y;
      y.x = fmaxf((acc[i][0] - mu) * rinv * gg[0] + ll[0], 0.f);
      y.y = fmaxf((acc[i][1] - mu) * rinv * gg[1] + ll[1], 0.f);
      y.z = fmaxf((acc[i][2] - mu) * rinv * gg[2] + ll[2], 0.f);
      y.w = fmaxf((acc[i][3] - mu) * rinv * gg[3] + ll[3], 0.f);
      *(float4*)&out[(size_t)gr * NH + tx * 4] = y;
    }
  }
}

// ---------------------------------------------------------------- final MLP: relu(h@W1.T+b1)@W2.T+b2
__global__ __launch_bounds__(256) void k_mlp(
    const float* __restrict__ h2, const float* __restrict__ W1,
    const float* __restrict__ b1, const float* __restrict__ W2,
    const float* __restrict__ b2, float* __restrict__ out)
{
  __shared__ float W1s[64 * 129];
  __shared__ float b1s[64];
  __shared__ float W2s[64];
  __shared__ float sx[4][128];
  int t = threadIdx.x;
  #pragma unroll
  for (int i = 0; i < 32; ++i) {
    int idx = t + 256 * i;
    int j = idx >> 7, k = idx & 127;
    W1s[j * 129 + k] = W1[idx];
  }
  if (t < 64) { b1s[t] = b1[t]; W2s[t] = W2[t]; }
  __syncthreads();
  int w = t >> 6, lane = t & 63;
  float b2v = b2[0];
  for (int it = 0; it < 8; ++it) {
    int r = blockIdx.x * 32 + it * 4 + w;
    sx[w][lane]      = h2[(size_t)r * NH + lane];
    sx[w][lane + 64] = h2[(size_t)r * NH + lane + 64];
    __syncthreads();
    float h = b1s[lane];
    #pragma unroll
    for (int k = 0; k < 128; ++k) h = fmaf(sx[w][k], W1s[lane * 129 + k], h);
    h = fmaxf(h, 0.f);
    float p = h * W2s[lane];
    #pragma unroll
    for (int o = 32; o > 0; o >>= 1) p += __shfl_down(p, o);
    if (lane == 0) out[r] = p + b2v;
    __syncthreads();
  }
}

// ---------------------------------------------------------------- launch
extern "C" void kernel_launch(void* const* d_in, const int* in_sizes, int n_in,
                              void* d_out, int out_size, void* d_ws, size_t ws_size,
                              hipStream_t stream)
{
  const float* emb_user = (const float*)d_in[0];
  const float* emb_item = (const float*)d_in[1];
  const float* Wl   = (const float*)d_in[2];   // [2,3,128,128]
  const float* bl   = (const float*)d_in[3];   // [2,3,128]
  const float* Wr   = (const float*)d_in[4];   // [2,3,128,128]
  const float* ln_g = (const float*)d_in[5];   // [2,2,128]
  const float* ln_b = (const float*)d_in[6];   // [2,2,128]
  const float* W1   = (const float*)d_in[7];   // [64,128]
  const float* b1   = (const float*)d_in[8];   // [64]
  const float* W2   = (const float*)d_in[9];   // [1,64]
  const float* b2   = (const float*)d_in[10];  // [1]
  const int* src_buys = (const int*)d_in[11];
  const int* dst_buys = (const int*)d_in[12];
  const int* src_rev  = (const int*)d_in[13];
  const int* dst_rev  = (const int*)d_in[14];
  const int* src_fol  = (const int*)d_in[15];
  const int* dst_fol  = (const int*)d_in[16];
  const int* tgt      = (const int*)d_in[17];
  float* outp = (float*)d_out;

  char* wp = (char*)d_ws;
  size_t ob = 0;
  auto take = [&](size_t bytes) -> void* {
    void* p = wp + ob;
    ob += (bytes + 255) & ~(size_t)255;
    return p;
  };
  int*   cnt     = (int*)  take((size_t)NNODE * 4);
  int*   offs    = (int*)  take((size_t)NNODE * 4);
  int*   cntBB   = (int*)  take((size_t)NRUN * 4);
  int*   sscan   = (int*)  take((size_t)(NRUN + 1) * 4);
  int*   partial = (int*)  take((size_t)NSCANB * 4);
  int*   pbase   = (int*)  take((size_t)NSCANB * 4);
  int*   esrc    = (int*)  take((size_t)3 * NEDGE * 4);
  float* Wrc     = (float*)take((size_t)2 * NH * NH * 4);
  float* bc      = (float*)take((size_t)2 * NH * 4);
  float* meanL1  = (float*)take((size_t)NNODE * NH * 4);
  float* xu1     = (float*)take((size_t)N_USERS * NH * 4);
  float* xi1     = (float*)take((size_t)N_ITEMS * NH * 4);
  float* mrev2   = (float*)take((size_t)NTGT * NH * 4);
  float* mfol2   = (float*)take((size_t)NTGT * NH * 4);
  float* xsel2   = (float*)take((size_t)NTGT * NH * 4);
  float* h2      = (float*)take((size_t)NTGT * NH * 4);
  // binned edge buffer (9.6 MB) aliases meanL1 (128 MB): consumed by k_csr
  // before k_agg1 writes meanL1.
  int*   binned  = (int*)meanL1;

  k_combine<<<(2 * NH * NH + 2 * NH + 255) / 256, 256, 0, stream>>>(Wr, bl, Wrc, bc);
  k_pcount<<<NBLK, 256, 0, stream>>>(dst_buys, dst_rev, dst_fol, cntBB);
  k_scanA<<<NSCANB, 256, 0, stream>>>(cntBB, partial);
  k_scanB<<<1, 256, 0, stream>>>(partial, pbase);
  k_scanC<<<NSCANB, 256, 0, stream>>>(cntBB, pbase, sscan);
  k_pfill<<<NBLK, 256, 0, stream>>>(
      src_buys, dst_buys, src_rev, dst_rev, src_fol, dst_fol, sscan, binned);
  k_csr<<<NBUCK, 256, 0, stream>>>(binned, sscan, cnt, offs, esrc);
  k_agg1<<<(NNODE + 7) / 8, 256, 0, stream>>>(offs, cnt, esrc, emb_user, emb_item, meanL1);

  // layer-1 item: relu(LN(mean_buys@Wl00.T + xi0@Wr00.T + bl00))
  k_gemm_ln<<<(N_ITEMS + 63) / 64, 256, 0, stream>>>(
      meanL1, Wl + 0 * NH * NH,
      emb_item, Wr + 0 * NH * NH,
      nullptr, nullptr,
      bl + 0 * NH, ln_g + 1 * NH, ln_b + 1 * NH, xi1, N_ITEMS);

  // layer-1 user: relu(LN(mean_rev@Wl01.T + mean_fol@Wl02.T + xu0@(Wr01+Wr02).T + bl01+bl02))
  k_gemm_ln<<<(N_USERS + 63) / 64, 256, 0, stream>>>(
      meanL1 + (size_t)BASE_REV * NH, Wl + 1 * NH * NH,
      meanL1 + (size_t)BASE_FOL * NH, Wl + 2 * NH * NH,
      emb_user, Wrc,
      bc, ln_g + 0 * NH, ln_b + 0 * NH, xu1, N_USERS);

  // layer-2 aggregation at targets only (item update is dead code)
  k_agg_tgt<<<(2 * NTGT + 7) / 8, 256, 0, stream>>>(tgt, offs, cnt, esrc, xu1, xi1, mrev2, mfol2, xsel2);

  // layer-2 user at targets
  k_gemm_ln<<<(NTGT + 63) / 64, 256, 0, stream>>>(
      mrev2, Wl + (1 * 3 + 1) * NH * NH,
      mfol2, Wl + (1 * 3 + 2) * NH * NH,
      xsel2, Wrc + NH * NH,
      bc + NH, ln_g + 2 * NH, ln_b + 2 * NH, h2, NTGT);

  // final MLP
  k_mlp<<<NTGT / 32, 256, 0, stream>>>(h2, W1, b1, W2, b2, outp);
}